// Round 6
// baseline (219.059 us; speedup 1.0000x reference)
//
#include <hip/hip_runtime.h>
#include <hip/hip_bf16.h>

// Problem: B=4, N=128, T=256, C=256, H=8, d=32. softmax over q-axis.
// S = V·(G/16)·K^T (G = Wq^T Wk, 1/16 pre-folded), P = softmax_q(S),
// O = P·(V·Wv^T), out = O·Wfc^T + b.   Fused: one block per (b,t), 8 waves.

typedef unsigned short u16;
typedef unsigned int   u32;
using bf16x8 = __attribute__((ext_vector_type(8))) short;
using f32x4  = __attribute__((ext_vector_type(4))) float;

#define MFMA(a, b, c) __builtin_amdgcn_mfma_f32_16x16x32_bf16((a), (b), (c), 0, 0, 0)

__device__ __forceinline__ u32 cvt2(float a, float b) {
    __hip_bfloat162 h = __float22bfloat162_rn(make_float2(a, b));
    u32 r; __builtin_memcpy(&r, &h, 4);
    return r;
}
__device__ __forceinline__ u16 bf1(float a) {
    __hip_bfloat16 h = __float2bfloat16(a);
    u16 r; __builtin_memcpy(&r, &h, 2);
    return r;
}

// ---- LDS map (u16 units), 60 KiB -> 2 blocks/CU ----
// SM_GW  @ 0     (4 KiB):  Gb [2 dt][4 dg][16][8] + Wvb (B-frag layouts)
// SM_KB  @ 2048  (8 KiB):  Kb  [8 kt][4 dg][16 klo][8 ds]
// SM_VBM @ 6144  (8 KiB):  Vb -> VMb in place [8 nt][4 dg][16][8]
// SM_VPT @ 10240 (8 KiB):  VpT [2 et][16 kg][16 elo][8 ks]
// SM_PB  @ 14336 (32 KiB): Pb  [8 qt][16 kg][16 qlo][8 ks]
// SM_STG @ 2048  (16 KiB): FC A-staging [8 w][2 buf][4 eg][16 m][8 es]
//                          (aliases Kb+VBM, dead at FC time)
#define SM_GW   0
#define SM_KB   2048
#define SM_VBM  6144
#define SM_VPT  10240
#define SM_PB   14336
#define SM_STG  2048
#define SM_TOTAL 30720

__global__ __launch_bounds__(512, 4) void attn_fc(
    const float* __restrict__ values, const float* __restrict__ keys,
    const u16* __restrict__ gwb,   // Gb/16 + Wvb (B-frag layouts, 2048 u16)
    const u16* __restrict__ wfcb,  // Wfc bf16 row-major [256][256]
    const float* __restrict__ bias,
    float* __restrict__ out)
{
    __shared__ __align__(16) u16 smu[SM_TOTAL];
    const int tid = threadIdx.x;
    const int w = tid >> 6, l = tid & 63, lo = l & 15, g = l >> 4;
    const int b = blockIdx.x >> 8, tt = blockIdx.x & 255;

    // stage Gb+Wvb (2048 u16 = 256 uint4)
    if (tid < 256) ((uint4*)smu)[tid] = ((const uint4*)gwb)[tid];

    // global V/K: thread (n, seg) loads 8 f32 of row n per head
    const int n = tid >> 2, seg = tid & 3;
    const size_t gb0 = ((size_t)(b * 128 + n) * 256 + tt) * 256 + seg * 8;
    float4 pv0 = *(const float4*)(values + gb0);
    float4 pv1 = *(const float4*)(values + gb0 + 4);
    float4 pk0 = *(const float4*)(keys + gb0);
    float4 pk1 = *(const float4*)(keys + gb0 + 4);

    const f32x4 z = {0.f, 0.f, 0.f, 0.f};
    const int rb = 4 * g + ((lo & 1) ? 2 : 0);
    u16* const kwr = smu + SM_KB  + (n >> 4) * 512 + seg * 128 + (n & 15) * 8;
    u16* const vwr = smu + SM_VBM + (n >> 4) * 512 + seg * 128 + (n & 15) * 8;
    u32 opk[8][4];   // packed bf16 O fragments (head loop is fully unrolled)

    #pragma unroll
    for (int h = 0; h < 8; ++h) {
        // ---- write Kb/Vb from prefetched regs ----
        *(uint4*)kwr = make_uint4(cvt2(pk0.x,pk0.y), cvt2(pk0.z,pk0.w),
                                  cvt2(pk1.x,pk1.y), cvt2(pk1.z,pk1.w));
        *(uint4*)vwr = make_uint4(cvt2(pv0.x,pv0.y), cvt2(pv0.z,pv0.w),
                                  cvt2(pv1.x,pv1.y), cvt2(pv1.z,pv1.w));
        __syncthreads();   // A: Kb, Vb (and Gb/Wvb at h=0) ready

        if (h < 7) {   // prefetch next head (latency hidden under compute)
            pv0 = *(const float4*)(values + gb0 + (h+1)*32);
            pv1 = *(const float4*)(values + gb0 + (h+1)*32 + 4);
            pk0 = *(const float4*)(keys   + gb0 + (h+1)*32);
            pk1 = *(const float4*)(keys   + gb0 + (h+1)*32 + 4);
        }

        // ---- VM = V@(G/16), Vp = V@Wv^T; wave w owns n-tile w ----
        {
            bf16x8 G0 = *(const bf16x8*)(smu + SM_GW +    0 + g*128 + lo*8);
            bf16x8 G1 = *(const bf16x8*)(smu + SM_GW +  512 + g*128 + lo*8);
            bf16x8 W0 = *(const bf16x8*)(smu + SM_GW + 1024 + g*128 + lo*8);
            bf16x8 W1 = *(const bf16x8*)(smu + SM_GW + 1536 + g*128 + lo*8);
            bf16x8 Av = *(const bf16x8*)(smu + SM_VBM + w*512 + g*128 + lo*8);
            f32x4 vm0 = MFMA(Av, G0, z), vm1 = MFMA(Av, G1, z);
            f32x4 vp0 = MFMA(Av, W0, z), vp1 = MFMA(Av, W1, z);
            #pragma unroll
            for (int dt = 0; dt < 2; ++dt) {   // VMb in place over Vb tile w (wave-private)
                f32x4 f = dt ? vm1 : vm0;
                float t0 = __shfl_xor(f[0],1), t1 = __shfl_xor(f[1],1),
                      t2 = __shfl_xor(f[2],1), t3 = __shfl_xor(f[3],1);
                u32 pa = (lo & 1) ? cvt2(t2, f[2]) : cvt2(f[0], t0);
                u32 pb_ = (lo & 1) ? cvt2(t3, f[3]) : cvt2(f[1], t1);
                u16* base = smu + SM_VBM + w*512 + (2*dt + (lo >> 3))*128 + (lo & 6);
                *(u32*)(base + rb*8)     = pa;
                *(u32*)(base + rb*8 + 8) = pb_;
            }
            #pragma unroll
            for (int et = 0; et < 2; ++et) {   // VpT (b64, k-consecutive pack)
                f32x4 f = et ? vp1 : vp0;
                uint2 pk_ = make_uint2(cvt2(f[0], f[1]), cvt2(f[2], f[3]));
                *(uint2*)(smu + SM_VPT + et*2048 + (2*w + (g >> 1))*128 + lo*8 + 4*(g & 1)) = pk_;
            }
        }
        __syncthreads();   // B: VMb, VpT ready

        // ---- S = VM @ K^T; wave w owns k-tile w (cols 16w..16w+15), all q ----
        f32x4 S[8];
        {
            bf16x8 Bk = *(const bf16x8*)(smu + SM_KB + w*512 + g*128 + lo*8);
            __builtin_amdgcn_s_setprio(1);
            #pragma unroll
            for (int tq = 0; tq < 8; ++tq) {
                bf16x8 Aq = *(const bf16x8*)(smu + SM_VBM + tq*512 + g*128 + lo*8);
                S[tq] = MFMA(Aq, Bk, z);
            }
            __builtin_amdgcn_s_setprio(0);
        }

        // ---- softmax over q (column = lane lo); Pb region distinct -> no barrier ----
        {
            float sum = 0.f;
            #pragma unroll
            for (int tq = 0; tq < 8; ++tq)
                #pragma unroll
                for (int r = 0; r < 4; ++r) {
                    float e = __expf(S[tq][r]);   // 1/16 folded into G; |S| << 1
                    S[tq][r] = e;
                    sum += e;
                }
            sum += __shfl_xor(sum, 16);
            sum += __shfl_xor(sum, 32);
            const float ci = 1.0f / sum;
            u16* pbw = smu + SM_PB + (2*w + (lo >> 3))*128 + rb*8 + (lo & 6);
            #pragma unroll
            for (int tq = 0; tq < 8; ++tq) {
                float e0 = S[tq][0]*ci, e1 = S[tq][1]*ci,
                      e2 = S[tq][2]*ci, e3 = S[tq][3]*ci;
                float t0 = __shfl_xor(e0,1), t1 = __shfl_xor(e1,1),
                      t2 = __shfl_xor(e2,1), t3 = __shfl_xor(e3,1);
                u32 pa = (lo & 1) ? cvt2(t2, e2) : cvt2(e0, t0);
                u32 pq = (lo & 1) ? cvt2(t3, e3) : cvt2(e1, t1);
                *(u32*)(pbw + tq*2048)     = pa;
                *(u32*)(pbw + tq*2048 + 8) = pq;
            }
        }
        __syncthreads();   // D: Pb ready

        // ---- O = P @ Vp; wave w owns q-tile w, e-tiles 0..1 ----
        f32x4 O0 = z, O1 = z;
        __builtin_amdgcn_s_setprio(1);
        #pragma unroll
        for (int c = 0; c < 4; ++c) {
            bf16x8 A  = *(const bf16x8*)(smu + SM_PB + w*2048 + (4*c+g)*128 + lo*8);
            bf16x8 B0 = *(const bf16x8*)(smu + SM_VPT +        (4*c+g)*128 + lo*8);
            bf16x8 B1 = *(const bf16x8*)(smu + SM_VPT + 2048 + (4*c+g)*128 + lo*8);
            O0 = MFMA(A, B0, O0);
            O1 = MFMA(A, B1, O1);
        }
        __builtin_amdgcn_s_setprio(0);

        // ---- pack O to bf16 pairs, keep in registers for fused FC ----
        #pragma unroll
        for (int et = 0; et < 2; ++et) {
            f32x4 f = et ? O1 : O0;
            float t0 = __shfl_xor(f[0],1), t1 = __shfl_xor(f[1],1),
                  t2 = __shfl_xor(f[2],1), t3 = __shfl_xor(f[3],1);
            opk[h][2*et]     = (lo & 1) ? cvt2(t2, f[2]) : cvt2(f[0], t0);
            opk[h][2*et + 1] = (lo & 1) ? cvt2(t3, f[3]) : cvt2(f[1], t1);
        }
    }

    // ---- fused FC: wave w owns out rows 16w..16w+15 (n-tile w), all 256 cols.
    //      A-frags come from opk via a wave-private LDS staging slot (in-order
    //      LDS ops within a wave -> no barriers). Staging aliases dead Kb/VBM. ----
    f32x4 acc[2][8];
    #pragma unroll
    for (int ch = 0; ch < 2; ++ch)
        #pragma unroll
        for (int v = 0; v < 8; ++v) {
            const float bi = bias[ch*128 + v*16 + lo];
            acc[ch][v] = f32x4{bi, bi, bi, bi};
        }
    #pragma unroll
    for (int h = 0; h < 8; ++h) {
        u16* stg = smu + SM_STG + w*1024 + (h & 1)*512;
        #pragma unroll
        for (int et = 0; et < 2; ++et) {
            u16* base = stg + (2*et + (lo >> 3))*128 + (lo & 6);
            *(u32*)(base + rb*8)     = opk[h][2*et];
            *(u32*)(base + rb*8 + 8) = opk[h][2*et + 1];
        }
        bf16x8 Afr = *(const bf16x8*)(stg + g*128 + lo*8);
        #pragma unroll
        for (int ch = 0; ch < 2; ++ch)
            #pragma unroll
            for (int v = 0; v < 8; ++v) {
                bf16x8 Br = *(const bf16x8*)(wfcb + (size_t)(ch*128 + v*16 + lo)*256 + h*32 + g*8);
                acc[ch][v] = MFMA(Afr, Br, acc[ch][v]);
            }
    }
    #pragma unroll
    for (int ch = 0; ch < 2; ++ch)
        #pragma unroll
        for (int v = 0; v < 8; ++v) {
            const int col = ch*128 + v*16 + lo;
            #pragma unroll
            for (int r = 0; r < 4; ++r)
                out[((size_t)(b*128 + w*16 + 4*g + r)*256 + tt)*256 + col] = acc[ch][v][r];
        }
}

// prep: Gb = (Wq^T@Wk)/16 bf16 B-layout (1/16 = exact 2^-4 scale);
//       Wvb = Wv^T bf16 B-layout; Wfc -> bf16 packed row-major.
__global__ void prep_kernel(const float* __restrict__ Wq, const float* __restrict__ Wk,
                            const float* __restrict__ Wv, const float* __restrict__ Wfc,
                            u16* __restrict__ gwb, u16* __restrict__ wfcb)
{
    const int tid = threadIdx.x;
    if (blockIdx.x == 0) {
        const int d = tid >> 3, c0 = (tid & 7) * 4;
        float a0 = 0.f, a1 = 0.f, a2 = 0.f, a3 = 0.f;
        for (int e = 0; e < 32; ++e) {
            const float wq = Wq[e*32 + d];
            a0 = fmaf(wq, Wk[e*32 + c0 + 0], a0);
            a1 = fmaf(wq, Wk[e*32 + c0 + 1], a1);
            a2 = fmaf(wq, Wk[e*32 + c0 + 2], a2);
            a3 = fmaf(wq, Wk[e*32 + c0 + 3], a3);
        }
        const float ga[4] = {a0 * 0.0625f, a1 * 0.0625f, a2 * 0.0625f, a3 * 0.0625f};
        #pragma unroll
        for (int i = 0; i < 4; ++i) {
            const int dp = c0 + i;   // Gb: B[k=d][col=dp] = G[d][dp]/16
            gwb[(dp >> 4)*512 + (d >> 3)*128 + (dp & 15)*8 + (d & 7)] = bf1(ga[i]);
            const int e = c0 + i;    // Wvb: B[k=d][col=e] = Wv[e][d]
            gwb[1024 + (e >> 4)*512 + (d >> 3)*128 + (e & 15)*8 + (d & 7)] = bf1(Wv[e*32 + d]);
        }
    }
    {   // Wfc f32 -> bf16 (packed row-major), 16 blocks x 256 thr x 16 f32
        const int seg = blockIdx.x * 256 + tid;      // 0..4095
        const float4* src = (const float4*)Wfc + seg*4;
        float4 x0 = src[0], x1 = src[1], x2 = src[2], x3 = src[3];
        ((uint4*)wfcb)[seg*2]     = make_uint4(cvt2(x0.x,x0.y), cvt2(x0.z,x0.w), cvt2(x1.x,x1.y), cvt2(x1.z,x1.w));
        ((uint4*)wfcb)[seg*2 + 1] = make_uint4(cvt2(x2.x,x2.y), cvt2(x2.z,x2.w), cvt2(x3.x,x3.y), cvt2(x3.z,x3.w));
    }
}

extern "C" void kernel_launch(void* const* d_in, const int* in_sizes, int n_in,
                              void* d_out, int out_size, void* d_ws, size_t ws_size,
                              hipStream_t stream) {
    const float* values = (const float*)d_in[0];
    const float* keys   = (const float*)d_in[1];
    // d_in[2] = query: shape-only in the reference (original code bug), unused.
    const float* Wq  = (const float*)d_in[3];
    const float* Wk  = (const float*)d_in[4];
    const float* Wv  = (const float*)d_in[5];
    const float* Wfc = (const float*)d_in[6];
    const float* bfc = (const float*)d_in[7];
    float* out = (float*)d_out;

    u16* gwb  = (u16*)d_ws;                       // Gb+Wvb bf16 B-layouts (4KB)
    u16* wfcb = (u16*)((char*)d_ws + 4096);       // Wfc bf16 (128KB)

    prep_kernel<<<16, 256, 0, stream>>>(Wq, Wk, Wv, Wfc, gwb, wfcb);
    attn_fc<<<1024, 512, 0, stream>>>(values, keys, gwb, wfcb, bfc, out);
}

// Round 7
// 176.131 us; speedup vs baseline: 1.2437x; 1.2437x over previous
//
#include <hip/hip_runtime.h>
#include <hip/hip_bf16.h>

// Problem: B=4, N=128, T=256, C=256, H=8, d=32. softmax over q-axis.
// S = V·(G/16)·K^T (G = Wq^T Wk, 1/16 pre-folded), P = softmax_q(S),
// O = P·(V·Wv^T), out = O·Wfc^T + b.

typedef unsigned short u16;
typedef unsigned int   u32;
using bf16x8 = __attribute__((ext_vector_type(8))) short;
using f32x4  = __attribute__((ext_vector_type(4))) float;

#define MFMA(a, b, c) __builtin_amdgcn_mfma_f32_16x16x32_bf16((a), (b), (c), 0, 0, 0)

__device__ __forceinline__ u32 cvt2(float a, float b) {
    __hip_bfloat162 h = __float22bfloat162_rn(make_float2(a, b));
    u32 r; __builtin_memcpy(&r, &h, 4);
    return r;
}
__device__ __forceinline__ u16 bf1(float a) {
    __hip_bfloat16 h = __float2bfloat16(a);
    u16 r; __builtin_memcpy(&r, &h, 2);
    return r;
}

// ---- LDS map (u16 units), 40 KiB total -> 4 blocks/CU, 3 barriers ----
// SM_VPT @ 0     (8 KiB):  VpT [2 et][16 kg][16 elo][8 ks]  (written pre-B2, read all-PV)
// SM_KB  @ 4096  (8 KiB):  Kb  [8 kt][4 dg][16 klo][8 ds]   (WAVE-PRIVATE: no barrier)
// SM_VBM @ 8192  (8 KiB):  Vb -> VMb in place               (write wave-private; read cross-wave post-B2)
// SM_PBA @ 12288 (16 KiB): P k=0..63   [8 qt][8 kgl][16 qlo][8 ks] (fresh region; ready at B4)
// SM_PBB @ 4096  (16 KiB): P k=64..127 (aliases Kb+VBM, dead after B4; ready at B6)
// SM_OB  @ 12288 (8 KiB):  Ob (aliases PbA, dead after B6; readback wave-private)
#define SM_VPT 0
#define SM_KB  4096
#define SM_VBM 8192
#define SM_PBA 12288
#define SM_PBB 4096
#define SM_OB  12288
#define SM_TOTAL 20480

__global__ __launch_bounds__(256, 4) void attn_mfma(
    const float* __restrict__ values, const float* __restrict__ keys,
    const u16* __restrict__ gwb,      // ws: Gb/16 (1024 u16) + Wvb (1024 u16), B-frag layouts
    u16* __restrict__ obf)            // O bf16: row m at u16 offset 512*m
{
    __shared__ __align__(16) u16 smu[SM_TOTAL];
    const int tid = threadIdx.x;
    const int x = blockIdx.x;
    // swizzle: all 8 h-blocks of one (b,t) land on the same XCD (x mod 8 fixed)
    const int h  = (x >> 3) & 7;
    const int bt = (x & 7) | ((x >> 6) << 3);   // 0..1023
    const int b  = bt >> 8, tt = bt & 255;
    const int w = tid >> 6, l = tid & 63, lo = l & 15, g = l >> 4;

    // ---- global V/K loads: thread (n, hf) holds 16 f32 of its row-half ----
    const int n  = tid >> 1;
    const int hf = tid & 1;
    const size_t row = (size_t)(b * 128 + n) * 256 + tt;
    const float4* gv = (const float4*)(values + row * 256 + h * 32 + hf * 16);
    const float4* gk = (const float4*)(keys   + row * 256 + h * 32 + hf * 16);
    float4 v0 = gv[0], v1 = gv[1], v2 = gv[2], v3 = gv[3];
    float4 k0 = gk[0], k1 = gk[1], k2 = gk[2], k3 = gk[3];

    // ---- G/Wv B-frags straight from global (4 KB, L2-hot across 8192 blocks) ----
    bf16x8 G0 = *(const bf16x8*)(gwb +    0 + g*128 + lo*8);
    bf16x8 G1 = *(const bf16x8*)(gwb +  512 + g*128 + lo*8);
    bf16x8 W0 = *(const bf16x8*)(gwb + 1024 + g*128 + lo*8);
    bf16x8 W1 = *(const bf16x8*)(gwb + 1536 + g*128 + lo*8);

    {   // Kb + Vb bf16 (subtiled [row][d]); WAVE-PRIVATE rows -> no barrier needed
        u16* kd = smu + SM_KB + (n >> 4) * 512 + (hf * 2) * 128 + (n & 15) * 8;
        *(uint4*)kd         = make_uint4(cvt2(k0.x,k0.y), cvt2(k0.z,k0.w), cvt2(k1.x,k1.y), cvt2(k1.z,k1.w));
        *(uint4*)(kd + 128) = make_uint4(cvt2(k2.x,k2.y), cvt2(k2.z,k2.w), cvt2(k3.x,k3.y), cvt2(k3.z,k3.w));
        u16* vd = smu + SM_VBM + (n >> 4) * 512 + (hf * 2) * 128 + (n & 15) * 8;
        *(uint4*)vd         = make_uint4(cvt2(v0.x,v0.y), cvt2(v0.z,v0.w), cvt2(v1.x,v1.y), cvt2(v1.z,v1.w));
        *(uint4*)(vd + 128) = make_uint4(cvt2(v2.x,v2.y), cvt2(v2.z,v2.w), cvt2(v3.x,v3.y), cvt2(v3.z,v3.w));
    }
    // no __syncthreads: VM-phase reads only this wave's Kb/Vb rows (in-wave LDS order)

    const f32x4 z = {0.f, 0.f, 0.f, 0.f};
    const int rb = 4*g + ((lo & 1) ? 2 : 0);

    // ---- VM = V@(G/16), Vp = V@Wv^T via MFMA; wave w owns tiles {2w, 2w+1};
    //      VMb overwrites Vb in place (wave-private, dependence-ordered) ----
    {
        #pragma unroll
        for (int q2 = 0; q2 < 2; ++q2) {
            const int qt = 2*w + q2;
            bf16x8 Av = *(const bf16x8*)(smu + SM_VBM + qt*512 + g*128 + lo*8);
            f32x4 vm0 = MFMA(Av, G0, z), vm1 = MFMA(Av, G1, z);
            f32x4 vp0 = MFMA(Av, W0, z), vp1 = MFMA(Av, W1, z);
            // VMb: xor-1 lane-pair pack -> b32 writes
            #pragma unroll
            for (int dt = 0; dt < 2; ++dt) {
                f32x4 f = dt ? vm1 : vm0;
                float t0 = __shfl_xor(f[0],1), t1 = __shfl_xor(f[1],1),
                      t2 = __shfl_xor(f[2],1), t3 = __shfl_xor(f[3],1);
                u32 pa = (lo & 1) ? cvt2(t2, f[2]) : cvt2(f[0], t0);
                u32 pb_ = (lo & 1) ? cvt2(t3, f[3]) : cvt2(f[1], t1);
                u16* base = smu + SM_VBM + qt*512 + (2*dt + (lo >> 3))*128 + (lo & 6);
                *(u32*)(base + rb*8)     = pa;
                *(u32*)(base + rb*8 + 8) = pb_;
            }
            // VpT: pack along rows (k-consecutive) -> b64 writes, 2-way banks
            #pragma unroll
            for (int et = 0; et < 2; ++et) {
                f32x4 f = et ? vp1 : vp0;
                uint2 pk = make_uint2(cvt2(f[0], f[1]), cvt2(f[2], f[3]));
                *(uint2*)(smu + SM_VPT + et*2048 + (2*qt + (g >> 1))*128 + lo*8 + 4*(g & 1)) = pk;
            }
        }
    }
    __syncthreads();   // B2: VMb + VpT ready (cross-wave)

    // ---- S = VM @ K^T via MFMA; wave w owns k-cols 32w..32w+31 (own Kb tiles), all q ----
    f32x4 S[8][2];
    {
        bf16x8 Bk0 = *(const bf16x8*)(smu + SM_KB + (2*w + 0)*512 + g*128 + lo*8);
        bf16x8 Bk1 = *(const bf16x8*)(smu + SM_KB + (2*w + 1)*512 + g*128 + lo*8);
        __builtin_amdgcn_s_setprio(1);
        #pragma unroll
        for (int tq = 0; tq < 8; ++tq) {
            bf16x8 Aq = *(const bf16x8*)(smu + SM_VBM + tq*512 + g*128 + lo*8);
            S[tq][0] = MFMA(Aq, Bk0, z);
            S[tq][1] = MFMA(Aq, Bk1, z);
        }
        __builtin_amdgcn_s_setprio(0);
    }

    // ---- softmax over q (1/16 pre-folded; no max-subtract: |S| small), pack in regs ----
    u32 pu[2][8][2];
    #pragma unroll
    for (int vi = 0; vi < 2; ++vi) {
        float sum = 0.f;
        #pragma unroll
        for (int tq = 0; tq < 8; ++tq)
            #pragma unroll
            for (int r = 0; r < 4; ++r) {
                float e = __expf(S[tq][vi][r]);
                S[tq][vi][r] = e;
                sum += e;
            }
        sum += __shfl_xor(sum, 16);
        sum += __shfl_xor(sum, 32);
        const float ci = 1.0f / sum;
        #pragma unroll
        for (int tq = 0; tq < 8; ++tq) {
            float e0 = S[tq][vi][0]*ci, e1 = S[tq][vi][1]*ci,
                  e2 = S[tq][vi][2]*ci, e3 = S[tq][vi][3]*ci;
            float t0 = __shfl_xor(e0,1), t1 = __shfl_xor(e1,1),
                  t2 = __shfl_xor(e2,1), t3 = __shfl_xor(e3,1);
            pu[vi][tq][0] = (lo & 1) ? cvt2(t2, e2) : cvt2(e0, t0);
            pu[vi][tq][1] = (lo & 1) ? cvt2(t3, e3) : cvt2(e1, t1);
        }
    }

    {
        const int kgl = (4*w + (lo >> 3)) & 7;   // round-local k-group (vi adds +2)
        u16* pb0 = smu + (w < 2 ? SM_PBA : SM_PBB) + kgl*128 + (lo & 6) + rb*8;
        if (w < 2) {   // PbA: k 0..63 into fresh region (no barrier needed before)
            #pragma unroll
            for (int vi = 0; vi < 2; ++vi)
                #pragma unroll
                for (int tq = 0; tq < 8; ++tq) {
                    *(u32*)(pb0 + vi*256 + tq*1024)     = pu[vi][tq][0];
                    *(u32*)(pb0 + vi*256 + tq*1024 + 8) = pu[vi][tq][1];
                }
        }
        __syncthreads();   // B4: PbA ready AND all S-phase reads of Kb/VMb done

        if (w >= 2) {  // PbB: k 64..127 over dead Kb+VBM (drains during PV-A)
            #pragma unroll
            for (int vi = 0; vi < 2; ++vi)
                #pragma unroll
                for (int tq = 0; tq < 8; ++tq) {
                    *(u32*)(pb0 + vi*256 + tq*1024)     = pu[vi][tq][0];
                    *(u32*)(pb0 + vi*256 + tq*1024 + 8) = pu[vi][tq][1];
                }
        }

        // ---- PV round A: O += P(:,0:64) @ Vp(0:64,:); wave w owns q-tiles 2w,2w+1 ----
        f32x4 O00 = z, O01 = z, O10 = z, O11 = z;
        __builtin_amdgcn_s_setprio(1);
        #pragma unroll
        for (int c = 0; c < 2; ++c) {
            const int kgo = (4*c + g)*128 + lo*8;
            bf16x8 A0 = *(const bf16x8*)(smu + SM_PBA + (2*w + 0)*1024 + kgo);
            bf16x8 A1 = *(const bf16x8*)(smu + SM_PBA + (2*w + 1)*1024 + kgo);
            bf16x8 B0 = *(const bf16x8*)(smu + SM_VPT + kgo);
            bf16x8 B1 = *(const bf16x8*)(smu + SM_VPT + 2048 + kgo);
            O00 = MFMA(A0, B0, O00);  O01 = MFMA(A0, B1, O01);
            O10 = MFMA(A1, B0, O10);  O11 = MFMA(A1, B1, O11);
        }
        __builtin_amdgcn_s_setprio(0);
        __syncthreads();   // B6: PbB ready AND PV-A reads of PbA done

        // ---- PV round B: k 64..127 ----
        __builtin_amdgcn_s_setprio(1);
        #pragma unroll
        for (int c = 0; c < 2; ++c) {
            const int kgo = (4*c + g)*128 + lo*8;
            bf16x8 A0 = *(const bf16x8*)(smu + SM_PBB + (2*w + 0)*1024 + kgo);
            bf16x8 A1 = *(const bf16x8*)(smu + SM_PBB + (2*w + 1)*1024 + kgo);
            bf16x8 B0 = *(const bf16x8*)(smu + SM_VPT + (8 + 4*c + g)*128 + lo*8);
            bf16x8 B1 = *(const bf16x8*)(smu + SM_VPT + 2048 + (8 + 4*c + g)*128 + lo*8);
            O00 = MFMA(A0, B0, O00);  O01 = MFMA(A0, B1, O01);
            O10 = MFMA(A1, B0, O10);  O11 = MFMA(A1, B1, O11);
        }
        __builtin_amdgcn_s_setprio(0);
        // no barrier: Ob aliases PbA (dead since B6); Ob rows are wave-private

        {   // Ob writes: xor-1 pack -> b32 (tiles 2w, 2w+1 = this wave's rows)
            #pragma unroll
            for (int fi = 0; fi < 4; ++fi) {
                f32x4 f = (fi == 0) ? O00 : (fi == 1) ? O01 : (fi == 2) ? O10 : O11;
                const int vi = fi >> 1, et = fi & 1;
                float t0 = __shfl_xor(f[0],1), t1 = __shfl_xor(f[1],1),
                      t2 = __shfl_xor(f[2],1), t3 = __shfl_xor(f[3],1);
                u32 pa = (lo & 1) ? cvt2(t2, f[2]) : cvt2(f[0], t0);
                u32 pq = (lo & 1) ? cvt2(t3, f[3]) : cvt2(f[1], t1);
                u16* ob = smu + SM_OB + (2*w + vi)*512 + (2*et + (lo >> 3))*128 + (lo & 6);
                *(u32*)(ob + rb*8)     = pa;
                *(u32*)(ob + rb*8 + 8) = pq;
            }
        }
        // no barrier: readback below touches only this wave's Ob tiles (in-wave LDS order)
    }

    {   // Ob -> global bf16, 32B per thread (rows n2 = 32w..32w+31: wave-private)
        const int n2 = tid >> 1;
        const int g0 = (tid & 1) * 2;
        const size_t m = (size_t)(b*128 + n2) * 256 + tt;   // same m as out row
        u16* dst = obf + m*512 + h*32 + g0*8;
        const u16* src = smu + SM_OB + (n2 >> 4)*512 + g0*128 + (n2 & 15)*8;
        *(uint4*)dst       = *(const uint4*)src;
        *(uint4*)(dst + 8) = *(const uint4*)(src + 128);
    }
}

// FC: out[m][col] = sum_k A[m][k]*Wfc[col][k] + bias[col].
// A (bf16) aliases out: row m's bf16 sits in the first 512B of out row m's 1KB slot.
// Blocks own 128-row slices exclusively; __syncthreads before stores keeps alias safe.
__global__ __launch_bounds__(512, 4) void fc_mfma(
    const u16* A, const u16* __restrict__ Wb,
    const float* __restrict__ bias, float* out)
{
    const int tid = threadIdx.x;
    const int w = tid >> 6, l = tid & 63, lo = l & 15, g = l >> 4;
    const int rowg = (w & 3) * 32;      // wave's 32 rows (2 MFMA row-tiles)
    const int colg = (w >> 2) * 128;    // wave's 128 cols (8 MFMA col-tiles)
    const size_t m0 = (size_t)blockIdx.x * 128;

    f32x4 acc[2][8];
    #pragma unroll
    for (int v = 0; v < 8; ++v) {
        const float bi = bias[colg + v*16 + lo];
        acc[0][v] = f32x4{bi, bi, bi, bi};
        acc[1][v] = f32x4{bi, bi, bi, bi};
    }
    #pragma unroll
    for (int c = 0; c < 8; ++c) {
        bf16x8 Ar0 = *(const bf16x8*)(A + (m0 + rowg +      lo)*512 + c*32 + g*8);
        bf16x8 Ar1 = *(const bf16x8*)(A + (m0 + rowg + 16 + lo)*512 + c*32 + g*8);
        bf16x8 Br[8];
        #pragma unroll
        for (int v = 0; v < 8; ++v)
            Br[v] = *(const bf16x8*)(Wb + (size_t)(colg + v*16 + lo)*256 + c*32 + g*8);
        #pragma unroll
        for (int v = 0; v < 8; ++v) {
            acc[0][v] = MFMA(Ar0, Br[v], acc[0][v]);
            acc[1][v] = MFMA(Ar1, Br[v], acc[1][v]);
        }
    }
    __syncthreads();   // all A-loads complete before any f32 store over the alias

    #pragma unroll
    for (int v = 0; v < 8; ++v)
        #pragma unroll
        for (int r = 0; r < 4; ++r) {
            out[(m0 + rowg +      4*g + r)*256 + colg + v*16 + lo] = acc[0][v][r];
            out[(m0 + rowg + 16 + 4*g + r)*256 + colg + v*16 + lo] = acc[1][v][r];
        }
}

// prep: Gb = (Wq^T@Wk)/16 bf16 B-layout (1/16 = exact 2^-4 scale);
//       Wvb = Wv^T bf16 B-layout; Wfc -> bf16 packed row-major.
__global__ void prep_kernel(const float* __restrict__ Wq, const float* __restrict__ Wk,
                            const float* __restrict__ Wv, const float* __restrict__ Wfc,
                            u16* __restrict__ gwb, u16* __restrict__ wfcb)
{
    const int tid = threadIdx.x;
    if (blockIdx.x == 0) {
        const int d = tid >> 3, c0 = (tid & 7) * 4;
        float a0 = 0.f, a1 = 0.f, a2 = 0.f, a3 = 0.f;
        for (int e = 0; e < 32; ++e) {
            const float wq = Wq[e*32 + d];
            a0 = fmaf(wq, Wk[e*32 + c0 + 0], a0);
            a1 = fmaf(wq, Wk[e*32 + c0 + 1], a1);
            a2 = fmaf(wq, Wk[e*32 + c0 + 2], a2);
            a3 = fmaf(wq, Wk[e*32 + c0 + 3], a3);
        }
        const float ga[4] = {a0 * 0.0625f, a1 * 0.0625f, a2 * 0.0625f, a3 * 0.0625f};
        #pragma unroll
        for (int i = 0; i < 4; ++i) {
            const int dp = c0 + i;   // Gb: B[k=d][col=dp] = G[d][dp]/16
            gwb[(dp >> 4)*512 + (d >> 3)*128 + (dp & 15)*8 + (d & 7)] = bf1(ga[i]);
            const int e = c0 + i;    // Wvb: B[k=d][col=e] = Wv[e][d]
            gwb[1024 + (e >> 4)*512 + (d >> 3)*128 + (e & 15)*8 + (d & 7)] = bf1(Wv[e*32 + d]);
        }
    }
    {   // Wfc f32 -> bf16 (packed row-major), 16 blocks x 256 thr x 16 f32
        const int seg = blockIdx.x * 256 + tid;      // 0..4095
        const float4* src = (const float4*)Wfc + seg*4;
        float4 x0 = src[0], x1 = src[1], x2 = src[2], x3 = src[3];
        ((uint4*)wfcb)[seg*2]     = make_uint4(cvt2(x0.x,x0.y), cvt2(x0.z,x0.w), cvt2(x1.x,x1.y), cvt2(x1.z,x1.w));
        ((uint4*)wfcb)[seg*2 + 1] = make_uint4(cvt2(x2.x,x2.y), cvt2(x2.z,x2.w), cvt2(x3.x,x3.y), cvt2(x3.z,x3.w));
    }
}

extern "C" void kernel_launch(void* const* d_in, const int* in_sizes, int n_in,
                              void* d_out, int out_size, void* d_ws, size_t ws_size,
                              hipStream_t stream) {
    const float* values = (const float*)d_in[0];
    const float* keys   = (const float*)d_in[1];
    // d_in[2] = query: shape-only in the reference (original code bug), unused.
    const float* Wq  = (const float*)d_in[3];
    const float* Wk  = (const float*)d_in[4];
    const float* Wv  = (const float*)d_in[5];
    const float* Wfc = (const float*)d_in[6];
    const float* bfc = (const float*)d_in[7];
    float* out = (float*)d_out;

    u16* gwb  = (u16*)d_ws;                       // Gb+Wvb bf16 B-layouts (4KB)
    u16* wfcb = (u16*)((char*)d_ws + 4096);       // Wfc bf16 (128KB)
    u16* obf  = (u16*)d_out;                      // O bf16, row m at u16 offset 512*m

    prep_kernel<<<16, 256, 0, stream>>>(Wq, Wk, Wv, Wfc, gwb, wfcb);
    attn_mfma<<<8192, 256, 0, stream>>>(values, keys, gwb, obf);
    fc_mfma<<<1024, 512, 0, stream>>>(obf, wfcb, bfc, out);
}